// Round 8
// baseline (20.740 us; speedup 1.0000x reference)
//
#include <hip/hip_runtime.h>
#include <math.h>

#define TT 512
#define EE 1024
#define AA 30
#define CH 32            // t-chunk length for the prefix scan
#define NC (TT / CH)     // 16 chunks per batch

typedef float f32x4 __attribute__((ext_vector_type(4)));

static __device__ __forceinline__ float dot4(f32x4 p, f32x4 q) {
    return p.x * q.x + p.y * q.y + p.z * q.z + p.w * q.w;
}

// ---- K1: es[b*T+t] = exp(relu(x[b,t,:] . W + bias))  (1 row per wave) ----
__global__ __launch_bounds__(256) void score_kernel(const float* __restrict__ x,
                                                    const float* __restrict__ W,
                                                    const float* __restrict__ bias,
                                                    float* __restrict__ es, int BT) {
    int row  = blockIdx.x * 4 + (threadIdx.x >> 6);
    int lane = threadIdx.x & 63;
    if (row >= BT) return;
    const f32x4* xr = reinterpret_cast<const f32x4*>(x + (size_t)row * EE);
    const f32x4* wr = reinterpret_cast<const f32x4*>(W);
    float acc = 0.f;
    #pragma unroll
    for (int k = 0; k < 4; ++k) {
        int i = lane + 64 * k;
        acc += dot4(xr[i], wr[i]);
    }
    #pragma unroll
    for (int off = 32; off; off >>= 1) acc += __shfl_xor(acc, off, 64);
    if (lane == 0) es[row] = __expf(fmaxf(acc + bias[0], 0.0f));
}

// ---- K2: chunked inclusive prefix  Pp[b,t,:] = sum_{tau=chunk_start..t} es*x ----
// One block per (b, chunk); thread owns one f32x4 column; the serial chain is
// FMA-only (loads are independent and pipeline ahead).
__global__ __launch_bounds__(256) void prefix_kernel(const float* __restrict__ x,
                                                     const float* __restrict__ es,
                                                     float* __restrict__ Pp,
                                                     float* __restrict__ C) {
    int blk = blockIdx.x;            // b*NC + tc
    int b = blk / NC, tc = blk - b * NC;
    int t0 = tc * CH;
    size_t rowoff = ((size_t)b * TT + t0) * (EE / 4);
    const f32x4* xb = reinterpret_cast<const f32x4*>(x) + rowoff + threadIdx.x;
    f32x4*       pp = reinterpret_cast<f32x4*>(Pp)      + rowoff + threadIdx.x;
    const float* e  = es + b * TT + t0;
    f32x4 acc = (f32x4)(0.f);
    #pragma unroll 8
    for (int i = 0; i < CH; ++i) {
        acc += e[i] * xb[(size_t)i * (EE / 4)];
        pp[(size_t)i * (EE / 4)] = acc;
    }
    reinterpret_cast<f32x4*>(C)[((size_t)b * NC + tc) * (EE / 4) + threadIdx.x] = acc;
}

// ---- K3: per span (1 wave): den = sum es[st..en]; num via prefix differences ----
template <int SWZ>
__global__ __launch_bounds__(256) void combine_kernel(const float* __restrict__ Pp,
                                                      const float* __restrict__ C,
                                                      const float* __restrict__ es,
                                                      const int* __restrict__ start,
                                                      const int* __restrict__ end,
                                                      float* __restrict__ out,
                                                      int S, int G) {
    int bid  = blockIdx.x;
    int wv   = threadIdx.x >> 6;
    int lane = threadIdx.x & 63;
    int b, s, g;
    if (SWZ) {                        // bid&7 -> XCD; XCD 0-3 own b=0, XCD 4-7 own b=1
        int xcd = bid & 7;
        b = xcd >> 2;
        int local = ((bid >> 3) << 2) | (xcd & 3);   // [0, S/4)
        s = local * 4 + wv;
        g = b * S + s;
    } else {
        g = bid * 4 + wv;
        if (g >= G) return;
        b = g / S;
        s = g - b * S;
    }

    int st = start[s];
    int nA = min(end[s] - st + 1, AA);
    int en = st + nA - 1;             // == end[s] (end <= T-1 by construction)

    float ev = (lane < nA) ? es[b * TT + st + lane] : 0.f;
    #pragma unroll
    for (int off = 32; off; off >>= 1) ev += __shfl_xor(ev, off, 64);
    float inv = 1.0f / ev;            // each es >= 1, so ev >= nA >= 1

    const f32x4* base = reinterpret_cast<const f32x4*>(Pp + (size_t)b * TT * EE) + lane;
    const f32x4* pe = base + (size_t)en * (EE / 4);
    f32x4 n0 = pe[0], n1 = pe[64], n2 = pe[128], n3 = pe[192];
    if (st & (CH - 1)) {              // subtract in-chunk prefix before st
        const f32x4* ps = base + (size_t)(st - 1) * (EE / 4);
        n0 -= ps[0]; n1 -= ps[64]; n2 -= ps[128]; n3 -= ps[192];
    }
    int cs = st / CH, ce = en / CH;   // window width <= 30 < CH -> ce <= cs+1
    if (ce > cs) {                    // add the full first chunk's total
        const f32x4* pc = reinterpret_cast<const f32x4*>(C + ((size_t)b * NC + cs) * EE) + lane;
        n0 += pc[0]; n1 += pc[64]; n2 += pc[128]; n3 += pc[192];
    }

    f32x4* op = reinterpret_cast<f32x4*>(out + (size_t)g * EE) + lane;
    __builtin_nontemporal_store(n0 * inv, op);
    __builtin_nontemporal_store(n1 * inv, op + 64);
    __builtin_nontemporal_store(n2 * inv, op + 128);
    __builtin_nontemporal_store(n3 * inv, op + 192);
}

// ---- Fallback: R7 fused kernel (any shape / tiny workspace) ----
template <int SWZ>
__global__ __launch_bounds__(256) void fused_span_kernel(const float* __restrict__ x,
                                                         const float* __restrict__ W,
                                                         const float* __restrict__ bias,
                                                         const int* __restrict__ start,
                                                         const int* __restrict__ end,
                                                         float* __restrict__ out,
                                                         int S, int G) {
    int bid  = blockIdx.x;
    int wv   = threadIdx.x >> 6;
    int lane = threadIdx.x & 63;
    int b, s, g;
    if (SWZ) {
        int xcd = bid & 7;
        b = xcd >> 2;
        int local = ((bid >> 3) << 2) | (xcd & 3);
        s = local * 4 + wv;
        g = b * S + s;
    } else {
        g = bid * 4 + wv;
        if (g >= G) return;
        b = g / S;
        s = g - b * S;
    }
    int st = start[s];
    int nA = min(end[s] - st + 1, AA);
    const f32x4* xb = reinterpret_cast<const f32x4*>(x + ((size_t)b * TT + st) * EE) + lane;
    const f32x4* wp = reinterpret_cast<const f32x4*>(W) + lane;
    f32x4 w0 = wp[0], w1 = wp[64], w2 = wp[128], w3 = wp[192];
    f32x4 a0 = (f32x4)(0.f), a1 = (f32x4)(0.f), a2 = (f32x4)(0.f), a3 = (f32x4)(0.f);
    float sum = 0.f, bsc = bias[0];
    for (int a = 0; a < nA; ++a) {
        const f32x4* r0 = xb + (size_t)a * (EE / 4);
        f32x4 v0 = r0[0], v1 = r0[64], v2 = r0[128], v3 = r0[192];
        float d0 = dot4(v0, w0) + dot4(v1, w1) + dot4(v2, w2) + dot4(v3, w3);
        #pragma unroll
        for (int off = 32; off; off >>= 1) d0 += __shfl_xor(d0, off, 64);
        float p0 = __expf(fmaxf(d0 + bsc, 0.f));
        sum += p0;
        a0 += p0 * v0; a1 += p0 * v1; a2 += p0 * v2; a3 += p0 * v3;
    }
    float inv = 1.0f / sum;
    f32x4* op = reinterpret_cast<f32x4*>(out + (size_t)g * EE) + lane;
    __builtin_nontemporal_store(a0 * inv, op);
    __builtin_nontemporal_store(a1 * inv, op + 64);
    __builtin_nontemporal_store(a2 * inv, op + 128);
    __builtin_nontemporal_store(a3 * inv, op + 192);
}

extern "C" void kernel_launch(void* const* d_in, const int* in_sizes, int n_in,
                              void* d_out, int out_size, void* d_ws, size_t ws_size,
                              hipStream_t stream) {
    const float* x     = (const float*)d_in[0];   // (B, T, E) f32
    const float* W     = (const float*)d_in[1];   // (E, 1)   f32
    const float* bias  = (const float*)d_in[2];   // (1,)     f32
    const int*   start = (const int*)d_in[3];     // (S,)     i32
    const int*   end   = (const int*)d_in[4];     // (S,)     i32
    float*       out   = (float*)d_out;           // (B, S, E) f32

    const int BT = in_sizes[0] / EE;              // B*T = 1024
    const int S  = in_sizes[3];                   // 2048
    const int B  = BT / TT;                       // 2
    const int G  = B * S;                         // 4096 spans

    float* es = (float*)d_ws;                                          // BT floats
    float* Pp = (float*)((char*)d_ws + 8192);                          // BT*EE floats
    float* C  = (float*)((char*)d_ws + 8192 + (size_t)BT * EE * 4);    // B*NC*EE floats
    size_t need = 8192 + (size_t)BT * EE * 4 + (size_t)B * NC * EE * 4;

    bool fast = (ws_size >= need) && (B * TT == BT) && (BT % 4 == 0);
    if (fast) {
        score_kernel<<<BT / 4, 256, 0, stream>>>(x, W, bias, es, BT);
        prefix_kernel<<<B * NC, 256, 0, stream>>>(x, es, Pp, C);
        if (B == 2 && S == 2048)
            combine_kernel<1><<<G / 4, 256, 0, stream>>>(Pp, C, es, start, end, out, S, G);
        else
            combine_kernel<0><<<(G + 3) / 4, 256, 0, stream>>>(Pp, C, es, start, end, out, S, G);
    } else {
        if (B == 2 && S == 2048)
            fused_span_kernel<1><<<G / 4, 256, 0, stream>>>(x, W, bias, start, end, out, S, G);
        else
            fused_span_kernel<0><<<(G + 3) / 4, 256, 0, stream>>>(x, W, bias, start, end, out, S, G);
    }
}

// Round 9
// 20.725 us; speedup vs baseline: 1.0007x; 1.0007x over previous
//
#include <hip/hip_runtime.h>
#include <math.h>

#define TT 512
#define EE 1024
#define AA 30
#define CH 16            // t-chunk length for the prefix scan
#define NC (TT / CH)     // 32 chunks per batch

typedef float f32x4 __attribute__((ext_vector_type(4)));

static __device__ __forceinline__ float dot4(f32x4 p, f32x4 q) {
    return p.x * q.x + p.y * q.y + p.z * q.z + p.w * q.w;
}

// ---- K1: per (b,chunk): scores for 16 rows (phase A, 4 waves x 4 rows), then
// ---- the in-chunk weighted prefix Pp and chunk total C (phase B, col-parallel).
__global__ __launch_bounds__(256) void score_prefix_kernel(const float* __restrict__ x,
                                                           const float* __restrict__ W,
                                                           const float* __restrict__ bias,
                                                           float* __restrict__ es,
                                                           float* __restrict__ Pp,
                                                           float* __restrict__ C) {
    int blk = blockIdx.x;                 // b*NC + tc
    int b = blk / NC, tc = blk - b * NC;
    int t0 = tc * CH;

    __shared__ float es_s[CH];
    int wv   = threadIdx.x >> 6;
    int lane = threadIdx.x & 63;

    // ---- phase A: scores ----
    const f32x4* wp = reinterpret_cast<const f32x4*>(W) + lane;
    f32x4 w0 = wp[0], w1 = wp[64], w2 = wp[128], w3 = wp[192];
    float bsc = bias[0];
    #pragma unroll
    for (int k = 0; k < CH / 4; ++k) {
        int idx = wv + 4 * k;             // row within chunk
        const f32x4* xr = reinterpret_cast<const f32x4*>(x + ((size_t)b * TT + t0 + idx) * EE) + lane;
        float d = dot4(xr[0], w0) + dot4(xr[64], w1) + dot4(xr[128], w2) + dot4(xr[192], w3);
        #pragma unroll
        for (int off = 32; off; off >>= 1) d += __shfl_xor(d, off, 64);
        if (lane == 0) {
            float e = __expf(fmaxf(d + bsc, 0.0f));
            es_s[idx] = e;
            es[b * TT + t0 + idx] = e;
        }
    }
    __syncthreads();

    // ---- phase B: weighted inclusive prefix over the chunk (thread = one f32x4 col) ----
    size_t rowoff = ((size_t)b * TT + t0) * (EE / 4) + threadIdx.x;
    const f32x4* xb = reinterpret_cast<const f32x4*>(x) + rowoff;
    f32x4*       pp = reinterpret_cast<f32x4*>(Pp)      + rowoff;
    f32x4 acc = (f32x4)(0.f);
    #pragma unroll
    for (int i = 0; i < CH; ++i) {
        acc += es_s[i] * xb[(size_t)i * (EE / 4)];
        pp[(size_t)i * (EE / 4)] = acc;
    }
    reinterpret_cast<f32x4*>(C)[((size_t)b * NC + tc) * (EE / 4) + threadIdx.x] = acc;
}

// ---- K2: per span (1 wave): den = sum es[st..en]; num via prefix differences.
// Window width <= 30 -> spans at most 3 chunks of 16: num = P[en] + f1*C[cs] + f2*C[cs+1] - fs*P[st-1].
__global__ __launch_bounds__(256) void combine_kernel(const float* __restrict__ Pp,
                                                      const float* __restrict__ C,
                                                      const float* __restrict__ es,
                                                      const int* __restrict__ start,
                                                      const int* __restrict__ end,
                                                      float* __restrict__ out,
                                                      int S, int G) {
    int g = blockIdx.x * 4 + (threadIdx.x >> 6);
    if (g >= G) return;
    int lane = threadIdx.x & 63;
    int b = g / S, s = g - b * S;

    int st = start[s];
    int nA = min(end[s] - st + 1, AA);
    int en = st + nA - 1;

    // denominator
    float ev = (lane < nA) ? es[b * TT + st + lane] : 0.f;
    #pragma unroll
    for (int off = 32; off; off >>= 1) ev += __shfl_xor(ev, off, 64);
    float inv = 1.0f / ev;                // each es >= 1 -> ev >= 1

    int cs = st >> 4, ce = en >> 4;
    float fs = (st & (CH - 1)) ? 1.f : 0.f;
    float f1 = (ce > cs)       ? 1.f : 0.f;
    float f2 = (ce > cs + 1)   ? 1.f : 0.f;
    int stm = st > 0 ? st - 1 : 0;        // when fs==0 the value is unused
    int c2  = cs + 1 < NC ? cs + 1 : NC - 1;

    const f32x4* pb = reinterpret_cast<const f32x4*>(Pp) + (size_t)b * TT * (EE / 4) + lane;
    const f32x4* cb = reinterpret_cast<const f32x4*>(C)  + (size_t)b * NC * (EE / 4) + lane;
    const f32x4* pe = pb + (size_t)en  * (EE / 4);
    const f32x4* ps = pb + (size_t)stm * (EE / 4);
    const f32x4* g1 = cb + (size_t)cs  * (EE / 4);
    const f32x4* g2 = cb + (size_t)c2  * (EE / 4);

    // 16 independent loads, one latency window
    f32x4 e0 = pe[0], e1 = pe[64], e2 = pe[128], e3 = pe[192];
    f32x4 s0 = ps[0], s1 = ps[64], s2 = ps[128], s3 = ps[192];
    f32x4 a0 = g1[0], a1 = g1[64], a2 = g1[128], a3 = g1[192];
    f32x4 b0 = g2[0], b1 = g2[64], b2 = g2[128], b3 = g2[192];

    f32x4 n0 = (e0 + f1 * a0 + f2 * b0 - fs * s0) * inv;
    f32x4 n1 = (e1 + f1 * a1 + f2 * b1 - fs * s1) * inv;
    f32x4 n2 = (e2 + f1 * a2 + f2 * b2 - fs * s2) * inv;
    f32x4 n3 = (e3 + f1 * a3 + f2 * b3 - fs * s3) * inv;

    f32x4* op = reinterpret_cast<f32x4*>(out + (size_t)g * EE) + lane;
    __builtin_nontemporal_store(n0, op);
    __builtin_nontemporal_store(n1, op + 64);
    __builtin_nontemporal_store(n2, op + 128);
    __builtin_nontemporal_store(n3, op + 192);
}

// ---- Fallback: R7 fused kernel (any shape / tiny workspace) ----
__global__ __launch_bounds__(256) void fused_span_kernel(const float* __restrict__ x,
                                                         const float* __restrict__ W,
                                                         const float* __restrict__ bias,
                                                         const int* __restrict__ start,
                                                         const int* __restrict__ end,
                                                         float* __restrict__ out,
                                                         int S, int G, int T) {
    int g = blockIdx.x * 4 + (threadIdx.x >> 6);
    if (g >= G) return;
    int lane = threadIdx.x & 63;
    int b = g / S, s = g - b * S;
    int st = start[s];
    int nA = min(end[s] - st + 1, AA);
    const f32x4* xb = reinterpret_cast<const f32x4*>(x + ((size_t)b * T + st) * EE) + lane;
    const f32x4* wp = reinterpret_cast<const f32x4*>(W) + lane;
    f32x4 w0 = wp[0], w1 = wp[64], w2 = wp[128], w3 = wp[192];
    f32x4 a0 = (f32x4)(0.f), a1 = (f32x4)(0.f), a2 = (f32x4)(0.f), a3 = (f32x4)(0.f);
    float sum = 0.f, bsc = bias[0];
    for (int a = 0; a < nA; ++a) {
        const f32x4* r0 = xb + (size_t)a * (EE / 4);
        f32x4 v0 = r0[0], v1 = r0[64], v2 = r0[128], v3 = r0[192];
        float d0 = dot4(v0, w0) + dot4(v1, w1) + dot4(v2, w2) + dot4(v3, w3);
        #pragma unroll
        for (int off = 32; off; off >>= 1) d0 += __shfl_xor(d0, off, 64);
        float p0 = __expf(fmaxf(d0 + bsc, 0.f));
        sum += p0;
        a0 += p0 * v0; a1 += p0 * v1; a2 += p0 * v2; a3 += p0 * v3;
    }
    float inv = 1.0f / sum;
    f32x4* op = reinterpret_cast<f32x4*>(out + (size_t)g * EE) + lane;
    __builtin_nontemporal_store(a0 * inv, op);
    __builtin_nontemporal_store(a1 * inv, op + 64);
    __builtin_nontemporal_store(a2 * inv, op + 128);
    __builtin_nontemporal_store(a3 * inv, op + 192);
}

extern "C" void kernel_launch(void* const* d_in, const int* in_sizes, int n_in,
                              void* d_out, int out_size, void* d_ws, size_t ws_size,
                              hipStream_t stream) {
    const float* x     = (const float*)d_in[0];   // (B, T, E) f32
    const float* W     = (const float*)d_in[1];   // (E, 1)   f32
    const float* bias  = (const float*)d_in[2];   // (1,)     f32
    const int*   start = (const int*)d_in[3];     // (S,)     i32
    const int*   end   = (const int*)d_in[4];     // (S,)     i32
    float*       out   = (float*)d_out;           // (B, S, E) f32

    const int BT = in_sizes[0] / EE;              // B*T = 1024
    const int S  = in_sizes[3];                   // 2048
    const int B  = BT / TT;                       // 2
    const int G  = B * S;                         // 4096 spans

    float* es = (float*)d_ws;                                          // BT floats
    float* Pp = (float*)((char*)d_ws + 8192);                          // BT*EE floats
    float* C  = (float*)((char*)d_ws + 8192 + (size_t)BT * EE * 4);    // B*NC*EE floats
    size_t need = 8192 + (size_t)BT * EE * 4 + (size_t)B * NC * EE * 4;

    bool fast = (ws_size >= need) && (B * TT == BT) && (B >= 1);
    if (fast) {
        score_prefix_kernel<<<B * NC, 256, 0, stream>>>(x, W, bias, es, Pp, C);
        combine_kernel<<<(G + 3) / 4, 256, 0, stream>>>(Pp, C, es, start, end, out, S, G);
    } else {
        fused_span_kernel<<<(G + 3) / 4, 256, 0, stream>>>(x, W, bias, start, end, out, S, G, BT / B);
    }
}